// Round 5
// baseline (98.684 us; speedup 1.0000x reference)
//
#include <hip/hip_runtime.h>

#define HH 32          // LSTM size
#define TT 20          // total steps (14 kernel + 3 down + 3 up)

typedef float v2f __attribute__((ext_vector_type(2)));

#define LOG2E  1.4426950408889634f
#define LN2    0.6931471805599453f

__device__ __forceinline__ float fsig(float x) {
    return __builtin_amdgcn_rcpf(1.0f + __builtin_amdgcn_exp2f(-x * LOG2E));
}
__device__ __forceinline__ float ftanh(float x) {
    return 1.0f - 2.0f * __builtin_amdgcn_rcpf(1.0f + __builtin_amdgcn_exp2f(x * (2.0f * LOG2E)));
}

// One block, ONE wave. Lane t owns ALL FOUR gate rows of gate-set (t&31)
// (W_hh in 128 VGPRs) -> no f/o shuffles. G[e] = W_ih@emb[e]+bias precomputed
// for all 15 embeddings (LDS, indexed per-lane) -> x never materializes; the
// idx->gates edge is one hidden ds_read_b128. Logits: lane computes the FULL
// 32-dot for class (t&7) (heads in 96 VGPRs, zero reduce shuffles); 8
// constant-lane shuffles then make all stats/argmax lane-local.
__global__ __launch_bounds__(64, 1) void controller_kernel(
    const float* __restrict__ w_ih,      // [128,32]
    const float* __restrict__ w_hh,      // [128,32]
    const float* __restrict__ b_ih,      // [128]
    const float* __restrict__ b_hh,      // [128]
    const float* __restrict__ g_emb,     // [1,32]
    const float* __restrict__ emb_kernel,// [8,32]
    const float* __restrict__ emb_down,  // [3,32]
    const float* __restrict__ emb_up,    // [3,32]
    const float* __restrict__ w_kernel,  // [8,32]
    const float* __restrict__ w_down,    // [3,32]
    const float* __restrict__ w_up,      // [3,32]
    const float* __restrict__ noise,     // [20,8]
    float* __restrict__ out)             // [22] = stats[2] ++ samples[20]
{
    const int t   = threadIdx.x;   // 0..63
    const int q   = t & 31;        // gate-set (lanes 32..63 duplicate)
    const int cls = t & 7;         // logit class this lane owns

    __shared__ __align__(16) float emb_s[15 * 32];   // 0..7 kern, 8..10 down, 11..13 up, 14 g_emb
    __shared__ __align__(16) float Gv[15 * 64 * 4];  // [e][lane][4] = per-lane (i,f,g,o) precomp
    __shared__ __align__(16) float h_s[32];
    __shared__ __align__(16) float gum_s[TT * 8];

    // ---- stage embeddings + gumbel noise ----
    for (int i = t; i < 15 * 32; i += 64) {
        const int r = i >> 5, j = i & 31;
        float v;
        if (r < 8)       v = emb_kernel[r * 32 + j];
        else if (r < 11) v = emb_down[(r - 8) * 32 + j];
        else if (r < 14) v = emb_up[(r - 11) * 32 + j];
        else             v = g_emb[j];
        emb_s[i] = v;
    }
    for (int i = t; i < TT * 8; i += 64) {
        const float u = noise[i];
        gum_s[i] = -logf(-logf(u * (1.0f - 1e-6f) + 1e-7f));
    }

    // ---- bias for my 4 rows ----
    float bias[4];
#pragma unroll
    for (int g = 0; g < 4; ++g) bias[g] = b_ih[q + 32 * g] + b_hh[q + 32 * g];

    // ---- W_ih rows (transient) -> G precompute ----
    {
        v2f wtmp[64];
#pragma unroll
        for (int g = 0; g < 4; ++g) {
            const float4* p = (const float4*)(w_ih + (q + 32 * g) * HH);
#pragma unroll
            for (int k8 = 0; k8 < 8; ++k8) {
                const float4 a = p[k8];
                wtmp[g * 16 + 2 * k8]     = (v2f){a.x, a.y};
                wtmp[g * 16 + 2 * k8 + 1] = (v2f){a.z, a.w};
            }
        }
        __syncthreads();   // emb_s ready
        for (int e = 0; e < 15; ++e) {
            const float4* ep = (const float4*)(emb_s + e * 32);
            v2f er[16];
#pragma unroll
            for (int k8 = 0; k8 < 8; ++k8) {
                const float4 a = ep[k8];
                er[2 * k8]     = (v2f){a.x, a.y};
                er[2 * k8 + 1] = (v2f){a.z, a.w};
            }
            v2f g0 = {0.f,0.f}, g1 = {0.f,0.f}, g2 = {0.f,0.f}, g3 = {0.f,0.f};
#pragma unroll
            for (int k = 0; k < 16; ++k) {
                g0 += wtmp[k]      * er[k];
                g1 += wtmp[16 + k] * er[k];
                g2 += wtmp[32 + k] * er[k];
                g3 += wtmp[48 + k] * er[k];
            }
            *(float4*)(Gv + (e * 64 + t) * 4) =
                make_float4(bias[0] + g0.x + g0.y, bias[1] + g1.x + g1.y,
                            bias[2] + g2.x + g2.y, bias[3] + g3.x + g3.y);
        }
    }
    __builtin_amdgcn_sched_barrier(0);   // keep W_hh/head loads from hoisting over G phase

    // ---- W_hh rows (resident) ----
    v2f whh[64];
#pragma unroll
    for (int g = 0; g < 4; ++g) {
        const float4* p = (const float4*)(w_hh + (q + 32 * g) * HH);
#pragma unroll
        for (int k8 = 0; k8 < 8; ++k8) {
            const float4 a = p[k8];
            whh[g * 16 + 2 * k8]     = (v2f){a.x, a.y};
            whh[g * 16 + 2 * k8 + 1] = (v2f){a.z, a.w};
        }
    }
    // ---- heads for my class (resident; down/up zero-padded for cls>=3) ----
    v2f hk[16], hd[16], hu[16];
#pragma unroll
    for (int k8 = 0; k8 < 8; ++k8) {
        const float4 a = ((const float4*)(w_kernel + cls * 32))[k8];
        hk[2 * k8] = (v2f){a.x, a.y}; hk[2 * k8 + 1] = (v2f){a.z, a.w};
        float4 b = make_float4(0.f, 0.f, 0.f, 0.f);
        float4 c = make_float4(0.f, 0.f, 0.f, 0.f);
        if (cls < 3) {
            b = ((const float4*)(w_down + cls * 32))[k8];
            c = ((const float4*)(w_up + cls * 32))[k8];
        }
        hd[2 * k8] = (v2f){b.x, b.y}; hd[2 * k8 + 1] = (v2f){b.z, b.w};
        hu[2 * k8] = (v2f){c.x, c.y}; hu[2 * k8 + 1] = (v2f){c.z, c.w};
    }

    // ---- init: h = 0, c = 0, first "embedding" = g_emb (G row 14) ----
    v2f hreg[16];
#pragma unroll
    for (int k = 0; k < 16; ++k) hreg[k] = (v2f){0.f, 0.f};
    float c_reg = 0.0f;
    float4 G4 = *(const float4*)(Gv + (14 * 64 + t) * 4);
    float lp_sum = 0.0f, ent_sum = 0.0f;

    for (int step = 0; step < TT; ++step) {
        // this step's gumbel noise (broadcast, hidden under FMA issue)
        const float4 gu0 = *(const float4*)(gum_s + step * 8);
        const float4 gu1 = *(const float4*)(gum_s + step * 8 + 4);

        // ---- A: gates = G4 + W_hh @ h (4 rows local, 64 pk_fma) ----
        v2f ai0 = {0.f,0.f}, ai1 = {0.f,0.f}, af0 = {0.f,0.f}, af1 = {0.f,0.f};
        v2f ag0 = {0.f,0.f}, ag1 = {0.f,0.f}, ao0 = {0.f,0.f}, ao1 = {0.f,0.f};
#pragma unroll
        for (int k = 0; k < 16; k += 2) {
            ai0 += whh[k]      * hreg[k];  ai1 += whh[k + 1]      * hreg[k + 1];
            af0 += whh[16 + k] * hreg[k];  af1 += whh[16 + k + 1] * hreg[k + 1];
            ag0 += whh[32 + k] * hreg[k];  ag1 += whh[32 + k + 1] * hreg[k + 1];
            ao0 += whh[48 + k] * hreg[k];  ao1 += whh[48 + k + 1] * hreg[k + 1];
        }
        const float ai = G4.x + ((ai0.x + ai0.y) + (ai1.x + ai1.y));
        const float af = G4.y + ((af0.x + af0.y) + (af1.x + af1.y));
        const float ag = G4.z + ((ag0.x + ag0.y) + (ag1.x + ag1.y));
        const float ao = G4.w + ((ao0.x + ao0.y) + (ao1.x + ao1.y));

        // ---- B: cell (all lanes duplicate; lanes 0..31 authoritative) ----
        const float ig = fsig(ai), fg = fsig(af), gg = ftanh(ag), og = fsig(ao);
        c_reg = fg * c_reg + ig * gg;
        const float hn = og * ftanh(c_reg);
        if (t < 32) h_s[t] = hn;
        __syncthreads();

        // ---- broadcast h into regs (used by logits AND next step's gates) ----
#pragma unroll
        for (int k8 = 0; k8 < 8; ++k8) {
            const float4 hv = ((const float4*)h_s)[k8];
            hreg[2 * k8]     = (v2f){hv.x, hv.y};
            hreg[2 * k8 + 1] = (v2f){hv.z, hv.w};
        }

        // ---- C: full logit for class cls (no reduce) ----
        const int n = (step < 14) ? 8 : 3;
        v2f s0 = {0.f,0.f}, s1 = {0.f,0.f};
        if (step < 14) {
#pragma unroll
            for (int k = 0; k < 16; k += 2) { s0 += hk[k] * hreg[k]; s1 += hk[k+1] * hreg[k+1]; }
        } else if (step < 17) {
#pragma unroll
            for (int k = 0; k < 16; k += 2) { s0 += hd[k] * hreg[k]; s1 += hd[k+1] * hreg[k+1]; }
        } else {
#pragma unroll
            for (int k = 0; k < 16; k += 2) { s0 += hu[k] * hreg[k]; s1 += hu[k+1] * hreg[k+1]; }
        }
        float l = (s0.x + s0.y) + (s1.x + s1.y);
        l = (cls < n) ? l : -1e9f;

        // ---- D: gather all 8 logits (constant-lane shuffles), all local after ----
        float lv[8];
#pragma unroll
        for (int k = 0; k < 8; ++k) lv[k] = __shfl(l, k);

        float S = 0.0f, Tm = 0.0f;
#pragma unroll
        for (int k = 0; k < 8; ++k) {
            const float e = __builtin_amdgcn_exp2f(lv[k] * LOG2E);  // masked -> 0
            S  += e;
            Tm += e * lv[k];
        }
        const float gum[8] = {gu0.x, gu0.y, gu0.z, gu0.w, gu1.x, gu1.y, gu1.z, gu1.w};
        int   idx = 0;
        float bv  = lv[0] + gum[0];
        float bl  = lv[0];
#pragma unroll
        for (int k = 1; k < 8; ++k) {
            const float v = lv[k] + gum[k];
            const bool take = v > bv;          // strict > keeps FIRST max index
            bv  = take ? v : bv;
            idx = take ? k : idx;
            bl  = take ? lv[k] : bl;
        }
        const float lse = __builtin_amdgcn_logf(S) * LN2;
        lp_sum  += bl - lse;
        ent_sum += lse - Tm * __builtin_amdgcn_rcpf(S);
        if (t == 0) out[2 + step] = (float)idx;

        // ---- E: next G row (latency hides under next step's FMA stream) ----
        const int nrb = ((step + 1) < 14) ? 0 : (((step + 1) < 17) ? 8 : 11);
        int nrow = nrb + idx;
        if (nrow > 14) nrow = 14;              // only possible at step 19 (unused)
        G4 = *(const float4*)(Gv + (nrow * 64 + t) * 4);
    }

    if (t == 0) {
        out[0] = lp_sum;
        out[1] = ent_sum;
    }
}

extern "C" void kernel_launch(void* const* d_in, const int* in_sizes, int n_in,
                              void* d_out, int out_size, void* d_ws, size_t ws_size,
                              hipStream_t stream) {
    (void)in_sizes; (void)n_in; (void)out_size; (void)d_ws; (void)ws_size;
    const float* w_ih       = (const float*)d_in[0];
    const float* w_hh       = (const float*)d_in[1];
    const float* b_ih       = (const float*)d_in[2];
    const float* b_hh       = (const float*)d_in[3];
    const float* g_emb      = (const float*)d_in[4];
    const float* emb_kernel = (const float*)d_in[5];
    const float* emb_down   = (const float*)d_in[6];
    const float* emb_up     = (const float*)d_in[7];
    const float* w_kernel   = (const float*)d_in[8];
    const float* w_down     = (const float*)d_in[9];
    const float* w_up       = (const float*)d_in[10];
    const float* noise      = (const float*)d_in[11];
    float* out = (float*)d_out;

    hipLaunchKernelGGL(controller_kernel, dim3(1), dim3(64), 0, stream,
                       w_ih, w_hh, b_ih, b_hh, g_emb, emb_kernel, emb_down,
                       emb_up, w_kernel, w_down, w_up, noise, out);
}